// Round 1
// baseline (7702.477 us; speedup 1.0000x reference)
//
#include <hip/hip_runtime.h>
#include <math.h>

#define VOCAB 32000
#define SEQ 2048
#define NL 8
#define NH 16
#define DM 1024
#define DFF 4096
#define DH 64
#define NB 2
#define MM (NB*SEQ)   /* 4096 rows in the flattened [B*S, D] activation */

typedef __attribute__((ext_vector_type(4))) float f32x4;
typedef __attribute__((ext_vector_type(8))) short s16x8;

__device__ __forceinline__ ushort f2b(float f) {
  union { float f; unsigned u; } c; c.f = f;
  unsigned u = c.u;
  return (ushort)((u + 0x7fffu + ((u >> 16) & 1u)) >> 16);
}

__device__ __forceinline__ f32x4 mfma16(s16x8 a, s16x8 b, f32x4 c) {
  return __builtin_amdgcn_mfma_f32_16x16x32_bf16(a, b, c, 0, 0, 0);
}

// ---------------- cast f32 -> bf16 (vectorized) ----------------
__global__ __launch_bounds__(256) void cast_kernel(const float* __restrict__ in,
                                                   ushort* __restrict__ out, int n4) {
  int i = blockIdx.x * 256 + threadIdx.x;
  if (i >= n4) return;
  float4 v = ((const float4*)in)[i];
  ushort4 o;
  o.x = f2b(v.x); o.y = f2b(v.y); o.z = f2b(v.z); o.w = f2b(v.w);
  ((ushort4*)out)[i] = o;
}

// ---------------- embedding: x = token_emb[id] + pos_emb ----------------
__global__ __launch_bounds__(256) void embed_kernel(const int* __restrict__ ids,
                                                    const float* __restrict__ emb,
                                                    const float* __restrict__ pos,
                                                    float* __restrict__ x) {
  const int row = blockIdx.x;            // b*SEQ + s
  const int s = row & (SEQ - 1);
  const int id = ids[row];
  const float4* e = (const float4*)(emb + (long)id * DM);
  const float4* p = (const float4*)(pos + (long)s * DM);
  float4* o = (float4*)(x + (long)row * DM);
  int c = threadIdx.x;                   // DM/4 == 256 == blockDim
  float4 a = e[c], b = p[c];
  float4 r; r.x = a.x + b.x; r.y = a.y + b.y; r.z = a.z + b.z; r.w = a.w + b.w;
  o[c] = r;
}

// ---------------- RMSNorm (f32 in, bf16 out) ----------------
__global__ __launch_bounds__(256) void rmsnorm_kernel(const float* __restrict__ x,
                                                      const float* __restrict__ w,
                                                      ushort* __restrict__ out) {
  const int row = blockIdx.x;
  const int t = threadIdx.x;
  float4 v = ((const float4*)(x + (long)row * DM))[t];
  float ss = v.x*v.x + v.y*v.y + v.z*v.z + v.w*v.w;
  #pragma unroll
  for (int m = 1; m < 64; m <<= 1) ss += __shfl_xor(ss, m);
  __shared__ float sm[4];
  if ((t & 63) == 0) sm[t >> 6] = ss;
  __syncthreads();
  float tot = sm[0] + sm[1] + sm[2] + sm[3];
  float rr = rsqrtf(tot * (1.0f / DM) + 1.1920929e-07f);   // torch eps=None -> f32 finfo eps
  float4 wv = ((const float4*)w)[t];
  ushort4 o;
  o.x = f2b(v.x * rr * wv.x); o.y = f2b(v.y * rr * wv.y);
  o.z = f2b(v.z * rr * wv.z); o.w = f2b(v.w * rr * wv.w);
  ((ushort4*)out)[(long)row * (DM/4) + t] = o;
}

// ---------------- GEMM: C[M,N] = A[M,K](bf16) @ B[K,N](bf16) ----------------
// MODE 0: f32 out. 1: f32 out + f32 residual. 2: bf16 out. 3: gelu(erf) -> bf16 out.
// BT: B given as [N,K] row-major (i.e. compute A @ B^T) -- used for tied logits.
#define LDK 40
template<int MODE, bool BT>
__global__ __launch_bounds__(256) void gemm_kernel(const ushort* __restrict__ A,
                                                   const ushort* __restrict__ Bm,
                                                   float* __restrict__ Cf,
                                                   ushort* __restrict__ Cb,
                                                   const float* __restrict__ R,
                                                   int Md, int Nd, int Kd) {
  __shared__ ushort sA[128 * LDK];
  __shared__ ushort sB[128 * LDK];   // stored as [n][k]
  const int tid = threadIdx.x;
  const int wave = tid >> 6, lane = tid & 63;
  const int quad = lane >> 4, l16 = lane & 15;
  const int wm = (wave >> 1) * 64, wn = (wave & 1) * 64;
  const long m0 = (long)blockIdx.y * 128, n0 = (long)blockIdx.x * 128;

  f32x4 acc[4][4];
  #pragma unroll
  for (int i = 0; i < 4; i++)
    #pragma unroll
    for (int j = 0; j < 4; j++) acc[i][j] = (f32x4){0.f, 0.f, 0.f, 0.f};

  for (long k0 = 0; k0 < Kd; k0 += 32) {
    __syncthreads();
    #pragma unroll
    for (int i = 0; i < 2; i++) {       // A tile 128x32
      int idx = i * 256 + tid;
      int r = idx >> 2, kc = (idx & 3) << 3;
      f32x4 v = *(const f32x4*)(A + (m0 + r) * (long)Kd + k0 + kc);
      *(f32x4*)(&sA[r * LDK + kc]) = v;
    }
    if (BT) {
      #pragma unroll
      for (int i = 0; i < 2; i++) {     // B is [N,K]: same pattern as A
        int idx = i * 256 + tid;
        int r = idx >> 2, kc = (idx & 3) << 3;
        f32x4 v = *(const f32x4*)(Bm + (n0 + r) * (long)Kd + k0 + kc);
        *(f32x4*)(&sB[r * LDK + kc]) = v;
      }
    } else {
      #pragma unroll
      for (int i = 0; i < 2; i++) {     // B is [K,N]: transpose into [n][k]
        int idx = i * 256 + tid;
        int kk = idx >> 4, nc = (idx & 15) << 3;
        s16x8 v = *(const s16x8*)(Bm + (k0 + kk) * (long)Nd + n0 + nc);
        #pragma unroll
        for (int j = 0; j < 8; j++) sB[(nc + j) * LDK + kk] = (ushort)v[j];
      }
    }
    __syncthreads();
    s16x8 af[4], bf[4];
    #pragma unroll
    for (int mi = 0; mi < 4; mi++)
      af[mi] = *(const s16x8*)(&sA[(wm + mi*16 + l16) * LDK + quad * 8]);
    #pragma unroll
    for (int ni = 0; ni < 4; ni++)
      bf[ni] = *(const s16x8*)(&sB[(wn + ni*16 + l16) * LDK + quad * 8]);
    #pragma unroll
    for (int mi = 0; mi < 4; mi++)
      #pragma unroll
      for (int ni = 0; ni < 4; ni++)
        acc[mi][ni] = mfma16(af[mi], bf[ni], acc[mi][ni]);
  }

  #pragma unroll
  for (int mi = 0; mi < 4; mi++) {
    #pragma unroll
    for (int ni = 0; ni < 4; ni++) {
      #pragma unroll
      for (int r = 0; r < 4; r++) {
        long row = m0 + wm + mi*16 + quad*4 + r;
        long col = n0 + wn + ni*16 + l16;
        float v = acc[mi][ni][r];
        if (MODE == 0) {
          Cf[row * Nd + col] = v;
        } else if (MODE == 1) {
          Cf[row * Nd + col] = v + R[row * Nd + col];
        } else if (MODE == 2) {
          Cb[row * Nd + col] = f2b(v);
        } else {
          float g = 0.5f * v * (1.0f + erff(v * 0.70710678118654752f));
          Cb[row * Nd + col] = f2b(g);
        }
      }
    }
  }
}

// ---------------- flash attention (causal, online softmax) ----------------
// grid: (SEQ/64, NB*NH); each wave owns 16 q rows, iterates 32-key tiles.
__global__ __launch_bounds__(256) void attn_kernel(const ushort* __restrict__ Q,
                                                   const ushort* __restrict__ K,
                                                   const ushort* __restrict__ Vv,
                                                   ushort* __restrict__ O) {
  __shared__ ushort sP[4 * 16 * 32];   // per-wave 16x32 P tile
  const int wave = threadIdx.x >> 6, lane = threadIdx.x & 63;
  const int quad = lane >> 4, l16 = lane & 15;
  const int bh = blockIdx.y, b = bh >> 4, h = bh & 15;
  const int qb = blockIdx.x * 64 + wave * 16;
  const long rowbase = (long)b * SEQ;
  const int colbase = h * DH;

  const ushort* qp = Q + (rowbase + qb + l16) * (long)DM + colbase;
  s16x8 aq0 = *(const s16x8*)(qp + quad * 8);
  s16x8 aq1 = *(const s16x8*)(qp + 32 + quad * 8);

  f32x4 oacc[4];
  #pragma unroll
  for (int f = 0; f < 4; f++) oacc[f] = (f32x4){0.f, 0.f, 0.f, 0.f};
  float mr[4] = {-3.0e38f, -3.0e38f, -3.0e38f, -3.0e38f};
  float lr[4] = {0.f, 0.f, 0.f, 0.f};
  const f32x4 zero = (f32x4){0.f, 0.f, 0.f, 0.f};

  for (int kb = 0; kb <= qb + 15; kb += 32) {
    f32x4 sacc[2];
    #pragma unroll
    for (int c = 0; c < 2; c++) {
      const ushort* kp = K + (rowbase + kb + c*16 + l16) * (long)DM + colbase;
      s16x8 bk0 = *(const s16x8*)(kp + quad * 8);
      s16x8 bk1 = *(const s16x8*)(kp + 32 + quad * 8);
      sacc[c] = mfma16(aq0, bk0, zero);
      sacc[c] = mfma16(aq1, bk1, sacc[c]);
    }
    float p[2][4];
    #pragma unroll
    for (int r = 0; r < 4; r++) {
      int qrow = qb + quad*4 + r;
      #pragma unroll
      for (int c = 0; c < 2; c++) {
        int kcol = kb + c*16 + l16;
        float sv = sacc[c][r] * 0.125f;          // 1/sqrt(64)
        if (kcol > qrow) sv = -3.0e38f;          // causal mask
        p[c][r] = sv;
      }
      float t = fmaxf(p[0][r], p[1][r]);
      t = fmaxf(t, __shfl_xor(t, 1));
      t = fmaxf(t, __shfl_xor(t, 2));
      t = fmaxf(t, __shfl_xor(t, 4));
      t = fmaxf(t, __shfl_xor(t, 8));
      float newm = fmaxf(mr[r], t);
      float alpha = __expf(mr[r] - newm);
      mr[r] = newm;
      float pv0 = __expf(p[0][r] - newm);
      float pv1 = __expf(p[1][r] - newm);
      p[0][r] = pv0; p[1][r] = pv1;
      float rs = pv0 + pv1;
      rs += __shfl_xor(rs, 1);
      rs += __shfl_xor(rs, 2);
      rs += __shfl_xor(rs, 4);
      rs += __shfl_xor(rs, 8);
      lr[r] = lr[r] * alpha + rs;
      #pragma unroll
      for (int f = 0; f < 4; f++) oacc[f][r] *= alpha;
    }
    // P: C-layout -> LDS -> A-layout (per-wave region; no cross-wave sync)
    #pragma unroll
    for (int r = 0; r < 4; r++)
      #pragma unroll
      for (int c = 0; c < 2; c++)
        sP[wave * 512 + (quad*4 + r) * 32 + c*16 + l16] = f2b(p[c][r]);
    s16x8 ap = *(const s16x8*)(&sP[wave * 512 + l16 * 32 + quad * 8]);
    #pragma unroll
    for (int f = 0; f < 4; f++) {
      s16x8 bv;
      #pragma unroll
      for (int j = 0; j < 8; j++)
        bv[j] = (short)Vv[(rowbase + kb + quad*8 + j) * (long)DM + colbase + f*16 + l16];
      oacc[f] = mfma16(ap, bv, oacc[f]);
    }
  }
  #pragma unroll
  for (int f = 0; f < 4; f++) {
    #pragma unroll
    for (int r = 0; r < 4; r++) {
      long row = rowbase + qb + quad*4 + r;
      float inv = 1.0f / lr[r];
      O[row * (long)DM + colbase + f*16 + l16] = f2b(oacc[f][r] * inv);
    }
  }
}

// ---------------- host ----------------
extern "C" void kernel_launch(void* const* d_in, const int* in_sizes, int n_in,
                              void* d_out, int out_size, void* d_ws, size_t ws_size,
                              hipStream_t stream) {
  const int*   ids  = (const int*)d_in[0];
  const float* temb = (const float*)d_in[1];
  const float* pemb = (const float*)d_in[2];
  const float* wq   = (const float*)d_in[3];
  const float* wk   = (const float*)d_in[4];
  const float* wv   = (const float*)d_in[5];
  const float* wo   = (const float*)d_in[6];
  const float* w1   = (const float*)d_in[7];
  const float* w2   = (const float*)d_in[8];
  const float* anw  = (const float*)d_in[9];
  const float* fnw  = (const float*)d_in[10];
  const float* finw = (const float*)d_in[11];
  float* logits = (float*)d_out;

  char* p = (char*)d_ws;
  auto take = [&](size_t n) { char* r = p; p += (n + 255) & ~(size_t)255; return r; };
  ushort* wq_b = (ushort*)take((size_t)NL*DM*DM*2);
  ushort* wk_b = (ushort*)take((size_t)NL*DM*DM*2);
  ushort* wv_b = (ushort*)take((size_t)NL*DM*DM*2);
  ushort* wo_b = (ushort*)take((size_t)NL*DM*DM*2);
  ushort* w1_b = (ushort*)take((size_t)NL*DM*DFF*2);
  ushort* w2_b = (ushort*)take((size_t)NL*DFF*DM*2);
  ushort* te_b = (ushort*)take((size_t)VOCAB*DM*2);
  float*  x    = (float*) take((size_t)MM*DM*4);
  ushort* hb   = (ushort*)take((size_t)MM*DM*2);
  ushort* qbuf = (ushort*)take((size_t)MM*DM*2);
  ushort* kbuf = (ushort*)take((size_t)MM*DM*2);
  ushort* vbuf = (ushort*)take((size_t)MM*DM*2);
  ushort* abuf = (ushort*)take((size_t)MM*DM*2);
  ushort* gbuf = (ushort*)take((size_t)MM*DFF*2);

  auto cast = [&](const float* src, ushort* dst, size_t n) {
    int n4 = (int)(n / 4);
    cast_kernel<<<(n4 + 255) / 256, 256, 0, stream>>>(src, dst, n4);
  };
  cast(wq, wq_b, (size_t)NL*DM*DM);
  cast(wk, wk_b, (size_t)NL*DM*DM);
  cast(wv, wv_b, (size_t)NL*DM*DM);
  cast(wo, wo_b, (size_t)NL*DM*DM);
  cast(w1, w1_b, (size_t)NL*DM*DFF);
  cast(w2, w2_b, (size_t)NL*DFF*DM);
  cast(temb, te_b, (size_t)VOCAB*DM);

  embed_kernel<<<MM, 256, 0, stream>>>(ids, temb, pemb, x);

  dim3 gQ(DM/128, MM/128);
  dim3 gF(DFF/128, MM/128);
  for (int l = 0; l < NL; l++) {
    size_t o1 = (size_t)l * DM * DM, o2 = (size_t)l * DM * DFF;
    rmsnorm_kernel<<<MM, 256, 0, stream>>>(x, anw + (size_t)l*DM, hb);
    gemm_kernel<2,false><<<gQ, 256, 0, stream>>>(hb, wq_b + o1, nullptr, qbuf, nullptr, MM, DM, DM);
    gemm_kernel<2,false><<<gQ, 256, 0, stream>>>(hb, wk_b + o1, nullptr, kbuf, nullptr, MM, DM, DM);
    gemm_kernel<2,false><<<gQ, 256, 0, stream>>>(hb, wv_b + o1, nullptr, vbuf, nullptr, MM, DM, DM);
    attn_kernel<<<dim3(SEQ/64, NB*NH), 256, 0, stream>>>(qbuf, kbuf, vbuf, abuf);
    gemm_kernel<1,false><<<gQ, 256, 0, stream>>>(abuf, wo_b + o1, x, nullptr, x, MM, DM, DM);
    rmsnorm_kernel<<<MM, 256, 0, stream>>>(x, fnw + (size_t)l*DM, hb);
    gemm_kernel<3,false><<<gF, 256, 0, stream>>>(hb, w1_b + o2, nullptr, gbuf, nullptr, MM, DFF, DM);
    gemm_kernel<1,false><<<gQ, 256, 0, stream>>>(gbuf, w2_b + o2, x, nullptr, x, MM, DM, DFF);
  }
  rmsnorm_kernel<<<MM, 256, 0, stream>>>(x, finw, hb);
  gemm_kernel<0,true><<<dim3(VOCAB/128, MM/128), 256, 0, stream>>>(hb, te_b, logits, nullptr, nullptr, MM, VOCAB, DM);
}